// Round 1
// baseline (5096.731 us; speedup 1.0000x reference)
//
#include <hip/hip_runtime.h>
#include <hip/hip_bf16.h>
#include <stdint.h>

// Problem constants
#define NTT   365
#define NGRID 2048
#define NXX   32
#define NHID  256

typedef __attribute__((ext_vector_type(8))) short bf16x8;
typedef __attribute__((ext_vector_type(4))) float f32x4;

// LDS layout (byte offsets). lds_h / lds_x0 are [64][256] bf16, XOR-swizzled.
#define H_OFF    0
#define X0_OFF   32768
#define STG_OFF  65536          // stage [64][40] bf16 (padded rows, 80 B)
#define WOUT_OFF 70656          // w_out [256] f32
#define SMEM_BYTES 71680

__device__ __forceinline__ int a_off(int row, int col) {
  // byte offset into a [64][256] bf16 tile, bank-conflict XOR swizzle
  return ((row << 9) + (col << 1)) ^ ((row & 7) << 4);
}
__device__ __forceinline__ unsigned short f2bf(float f) {
  unsigned u = __builtin_bit_cast(unsigned, f);
  return (unsigned short)((u + 0x7FFFu + ((u >> 16) & 1u)) >> 16);  // RNE
}
__device__ __forceinline__ float bf2f(unsigned short s) {
  unsigned u = ((unsigned)s) << 16;
  return __builtin_bit_cast(float, u);
}
__device__ __forceinline__ float sigm(float x) {
  return 1.0f / (1.0f + exp2f(-1.4426950408889634f * x));
}
__device__ __forceinline__ float tanh_f(float x) {
  return 2.0f / (1.0f + exp2f(-2.8853900817779268f * x)) - 1.0f;
}
__device__ __forceinline__ bf16x8 pack8(float4 a, float4 b) {
  bf16x8 r;
  r[0] = (short)f2bf(a.x); r[1] = (short)f2bf(a.y);
  r[2] = (short)f2bf(a.z); r[3] = (short)f2bf(a.w);
  r[4] = (short)f2bf(b.x); r[5] = (short)f2bf(b.y);
  r[6] = (short)f2bf(b.z); r[7] = (short)f2bf(b.w);
  return r;
}

// Persistent fused LSTM.
// Grid: 256 blocks = 32 row-groups x 8 members. Block: 512 thr = 8 waves.
// Member m owns h-cols [32m,32m+32) -> 128 gate rows, weights in VGPRs.
// Gates computed TRANSPOSED: D[n][row] = sum_k W[n][k] * A[row][k],
//   A = [h_{t-1} (k<256) | x0_t (k>=256)], so C-frag reg index == gate id.
extern "C" __global__ void __launch_bounds__(512, 2)
kuai_lstm(const float* __restrict__ x, const float* __restrict__ w_in,
          const float* __restrict__ b_in, const float* __restrict__ w_ih,
          const float* __restrict__ w_hh, const float* __restrict__ b_ih,
          const float* __restrict__ b_hh, const float* __restrict__ w_out,
          const float* __restrict__ b_out, float* __restrict__ out,
          unsigned* __restrict__ cnt, unsigned long long* __restrict__ hbuf) {
  extern __shared__ char smem[];
  const int tid = threadIdx.x;
  const int l   = tid & 63;
  const int l15 = l & 15;
  const int l4  = l >> 4;
  const int w   = tid >> 6;   // wave 0..7
  const int wq  = w & 3;      // gate-col quarter (n in [32wq,32wq+32))
  const int wr  = w >> 2;     // row half (rows [32wr,32wr+32))

  const int bid = blockIdx.x;
  const int xcd = bid & 7;          // keep group members on same XCD (perf only)
  const int t2  = bid >> 3;
  const int q   = t2 >> 3;          // group-within-xcd 0..3
  const int m   = t2 & 7;           // member 0..7
  const int grp = xcd * 4 + q;      // row-group 0..31
  const int r0  = grp * 64;

  // ---------------- prologue ----------------
  if (tid < 64) {
    float4 v = *(const float4*)(w_out + tid * 4);
    *(float4*)(smem + WOUT_OFF + tid * 16) = v;
  }
  const float b_out_v = b_out[0];

  // Gate-weight fragments, resident in VGPRs. n local in [0,128):
  // jj = n>>2 (local h-col), g = n&3 (gate), gc = g*256 + 32m + jj.
  bf16x8 Wf[2][16];
#pragma unroll
  for (int i = 0; i < 2; ++i) {
    int n  = 32 * wq + 16 * i + l15;
    int gc = (n & 3) * 256 + 32 * m + (n >> 2);
    const float* bh = w_hh + (size_t)gc * 256;
    const float* bi = w_ih + (size_t)gc * 256;
#pragma unroll
    for (int kc = 0; kc < 16; ++kc) {
      int k = kc * 32 + l4 * 8;
      const float* p = (kc < 8) ? (bh + k) : (bi + (k - 256));
      Wf[i][kc] = pack8(*(const float4*)p, *(const float4*)(p + 4));
    }
  }
  // w_in fragments (A-operand of transposed x0 GEMM) + b_in per-lane
  bf16x8 WinF[4];
  float  binv[4][4];
#pragma unroll
  for (int ii = 0; ii < 4; ++ii) {
    int xct = 4 * wq + ii;
    const float* p = w_in + (size_t)(16 * xct + l15) * 32 + l4 * 8;
    WinF[ii] = pack8(*(const float4*)p, *(const float4*)(p + 4));
#pragma unroll
    for (int r = 0; r < 4; ++r)
      binv[ii][r] = b_in[16 * xct + 4 * l4 + r];
  }
  // gate bias (b_ih + b_hh) per accum reg
  float bsv[2][4];
#pragma unroll
  for (int i = 0; i < 2; ++i)
#pragma unroll
    for (int r = 0; r < 4; ++r) {
      int gc = r * 256 + 32 * m + (8 * wq + 4 * i + l4);
      bsv[i][r] = b_ih[gc] + b_hh[gc];
    }

  float creg[2][2] = {{0.f, 0.f}, {0.f, 0.f}};
  const int srow = tid >> 3;  // 0..63
  const int sseg = tid & 7;   // 0..7
  __syncthreads();

  // ---------------- time loop ----------------
  for (int t = 0; t < NTT; ++t) {
    // ---- X phase: x0 = relu(x_t @ w_in^T + b_in), transposed MFMA ----
    bf16x8 xf[2];
#pragma unroll
    for (int j = 0; j < 2; ++j) {
      const float* xp = x + ((size_t)t * NGRID + (r0 + 32 * wr + 16 * j + l15)) * NXX + l4 * 8;
      xf[j] = pack8(*(const float4*)xp, *(const float4*)(xp + 4));
    }
    f32x4 xacc[4][2];
#pragma unroll
    for (int ii = 0; ii < 4; ++ii)
#pragma unroll
      for (int j = 0; j < 2; ++j) {
        xacc[ii][j][0] = binv[ii][0]; xacc[ii][j][1] = binv[ii][1];
        xacc[ii][j][2] = binv[ii][2]; xacc[ii][j][3] = binv[ii][3];
      }
#pragma unroll
    for (int ii = 0; ii < 4; ++ii)
#pragma unroll
      for (int j = 0; j < 2; ++j)
        xacc[ii][j] = __builtin_amdgcn_mfma_f32_16x16x32_bf16(WinF[ii], xf[j], xacc[ii][j], 0, 0, 0);
    // relu -> bf16 -> lds_x0 (x0 col = 16*xct + 4*l4 + reg)
#pragma unroll
    for (int ii = 0; ii < 4; ++ii)
#pragma unroll
      for (int j = 0; j < 2; ++j) {
        int row = 32 * wr + 16 * j + l15;
        int col = 16 * (4 * wq + ii) + 4 * l4;
        unsigned short h0 = f2bf(fmaxf(xacc[ii][j][0], 0.f));
        unsigned short h1 = f2bf(fmaxf(xacc[ii][j][1], 0.f));
        unsigned short h2 = f2bf(fmaxf(xacc[ii][j][2], 0.f));
        unsigned short h3 = f2bf(fmaxf(xacc[ii][j][3], 0.f));
        uint64_t pk = (uint64_t)h0 | ((uint64_t)h1 << 16) | ((uint64_t)h2 << 32) | ((uint64_t)h3 << 48);
        *(uint64_t*)(smem + X0_OFF + a_off(row, col)) = pk;
      }
    __syncthreads();

    // gate accumulators (transposed): reg r == gate r for (jj,row)
    f32x4 acc[2][2];
#pragma unroll
    for (int i = 0; i < 2; ++i)
#pragma unroll
      for (int j = 0; j < 2; ++j) {
        acc[i][j][0] = bsv[i][0]; acc[i][j][1] = bsv[i][1];
        acc[i][j][2] = bsv[i][2]; acc[i][j][3] = bsv[i][3];
      }
    // x0 half of K (kc 8..15) — no dependence on peers
#pragma unroll
    for (int kc = 0; kc < 8; ++kc)
#pragma unroll
      for (int j = 0; j < 2; ++j) {
        bf16x8 bfrag = *(const bf16x8*)(smem + X0_OFF + a_off(32 * wr + 16 * j + l15, kc * 32 + l4 * 8));
        acc[0][j] = __builtin_amdgcn_mfma_f32_16x16x32_bf16(Wf[0][kc + 8], bfrag, acc[0][j], 0, 0, 0);
        acc[1][j] = __builtin_amdgcn_mfma_f32_16x16x32_bf16(Wf[1][kc + 8], bfrag, acc[1][j], 0, 0, 0);
      }

    if (t > 0) {
      // ---- wait for peers' h_{t-1}, stage into lds_h ----
      if (tid == 0) {
        unsigned tgt = 8u * (unsigned)((t + 1) >> 1);
        while (__hip_atomic_load(cnt + grp * 2 + ((t - 1) & 1), __ATOMIC_ACQUIRE,
                                 __HIP_MEMORY_SCOPE_AGENT) < tgt)
          __builtin_amdgcn_s_sleep(1);
      }
      __syncthreads();
      const unsigned long long* src =
          hbuf + (size_t)((t - 1) & 1) * 131072 + (size_t)(r0 + srow) * 64 + sseg * 8;
#pragma unroll
      for (int u = 0; u < 8; ++u) {
        unsigned long long v = __hip_atomic_load(src + u, __ATOMIC_RELAXED, __HIP_MEMORY_SCOPE_AGENT);
        *(uint64_t*)(smem + H_OFF + a_off(srow, sseg * 32 + u * 4)) = v;
      }
      __syncthreads();
      // h half of K (kc 0..7)
#pragma unroll
      for (int kc = 0; kc < 8; ++kc)
#pragma unroll
        for (int j = 0; j < 2; ++j) {
          bf16x8 bfrag = *(const bf16x8*)(smem + H_OFF + a_off(32 * wr + 16 * j + l15, kc * 32 + l4 * 8));
          acc[0][j] = __builtin_amdgcn_mfma_f32_16x16x32_bf16(Wf[0][kc], bfrag, acc[0][j], 0, 0, 0);
          acc[1][j] = __builtin_amdgcn_mfma_f32_16x16x32_bf16(Wf[1][kc], bfrag, acc[1][j], 0, 0, 0);
        }
      // out[t-1] = h_{t-1} . w_out + b_out (h_{t-1} is in lds_h)
      {
        float s = 0.f;
#pragma unroll
        for (int u = 0; u < 8; ++u) {
          uint64_t hv = *(const uint64_t*)(smem + H_OFF + a_off(srow, sseg * 32 + u * 4));
          const float* wo = (const float*)(smem + WOUT_OFF) + sseg * 32 + u * 4;
          s += bf2f((unsigned short)(hv      )) * wo[0];
          s += bf2f((unsigned short)(hv >> 16)) * wo[1];
          s += bf2f((unsigned short)(hv >> 32)) * wo[2];
          s += bf2f((unsigned short)(hv >> 48)) * wo[3];
        }
        s += __shfl_xor(s, 1);
        s += __shfl_xor(s, 2);
        s += __shfl_xor(s, 4);
        if (sseg == 0) out[(size_t)(t - 1) * NGRID + r0 + srow] = s + b_out_v;
      }
    }

    // ---- nonlinearities: regs 0..3 of each acc are (i,f,g,o) ----
#pragma unroll
    for (int i = 0; i < 2; ++i)
#pragma unroll
      for (int j = 0; j < 2; ++j) {
        float gi = acc[i][j][0], gf = acc[i][j][1], gg = acc[i][j][2], go = acc[i][j][3];
        float cn = sigm(gf) * creg[i][j] + sigm(gi) * tanh_f(gg);
        float hn = sigm(go) * tanh_f(cn);
        creg[i][j] = cn;
        int row = 32 * wr + 16 * j + l15;
        int jjl = 8 * wq + 4 * i + l4;   // local h-col 0..31
        *(unsigned short*)(smem + STG_OFF + row * 80 + jjl * 2) = f2bf(hn);
      }
    __syncthreads();
    // ---- publish h_t (own 32-col chunk), agent-scope ----
    {
      uint64_t v = *(const uint64_t*)(smem + STG_OFF + srow * 80 + sseg * 8);
      unsigned long long* dst =
          hbuf + (size_t)(t & 1) * 131072 + (size_t)(r0 + srow) * 64 + m * 8 + sseg;
      __hip_atomic_store(dst, v, __ATOMIC_RELAXED, __HIP_MEMORY_SCOPE_AGENT);
    }
    __syncthreads();  // drains vmcnt: all stores globally visible
    if (tid == 0)
      __hip_atomic_fetch_add(cnt + grp * 2 + (t & 1), 1u, __ATOMIC_RELEASE,
                             __HIP_MEMORY_SCOPE_AGENT);
  }

  // ---------------- epilogue: out[NT-1] ----------------
  if (tid == 0) {
    unsigned tgt = 8u * (unsigned)((NTT + 1) >> 1);
    while (__hip_atomic_load(cnt + grp * 2 + ((NTT - 1) & 1), __ATOMIC_ACQUIRE,
                             __HIP_MEMORY_SCOPE_AGENT) < tgt)
      __builtin_amdgcn_s_sleep(1);
  }
  __syncthreads();
  {
    const unsigned long long* src =
        hbuf + (size_t)((NTT - 1) & 1) * 131072 + (size_t)(r0 + srow) * 64 + sseg * 8;
    float s = 0.f;
#pragma unroll
    for (int u = 0; u < 8; ++u) {
      unsigned long long hv = __hip_atomic_load(src + u, __ATOMIC_RELAXED, __HIP_MEMORY_SCOPE_AGENT);
      const float* wo = (const float*)(smem + WOUT_OFF) + sseg * 32 + u * 4;
      s += bf2f((unsigned short)(hv      )) * wo[0];
      s += bf2f((unsigned short)(hv >> 16)) * wo[1];
      s += bf2f((unsigned short)(hv >> 32)) * wo[2];
      s += bf2f((unsigned short)(hv >> 48)) * wo[3];
    }
    s += __shfl_xor(s, 1);
    s += __shfl_xor(s, 2);
    s += __shfl_xor(s, 4);
    if (sseg == 0) out[(size_t)(NTT - 1) * NGRID + r0 + srow] = s + b_out_v;
  }
}

extern "C" void kernel_launch(void* const* d_in, const int* in_sizes, int n_in,
                              void* d_out, int out_size, void* d_ws, size_t ws_size,
                              hipStream_t stream) {
  const float* x     = (const float*)d_in[0];
  const float* w_in  = (const float*)d_in[1];
  const float* b_in  = (const float*)d_in[2];
  const float* w_ih  = (const float*)d_in[3];
  const float* w_hh  = (const float*)d_in[4];
  const float* b_ih  = (const float*)d_in[5];
  const float* b_hh  = (const float*)d_in[6];
  const float* w_out = (const float*)d_in[7];
  const float* b_out = (const float*)d_in[8];
  float* out = (float*)d_out;

  // ws layout: [0,1024)   sync counters (zeroed every launch)
  //            [1024, +2MB) h ping-pong buffers (bf16, written before read)
  unsigned* cnt = (unsigned*)d_ws;
  unsigned long long* hbuf = (unsigned long long*)((char*)d_ws + 1024);

  hipMemsetAsync(d_ws, 0, 1024, stream);

  hipFuncSetAttribute((const void*)kuai_lstm,
                      hipFuncAttributeMaxDynamicSharedMemorySize, SMEM_BYTES);

  void* args[] = {(void*)&x, (void*)&w_in, (void*)&b_in, (void*)&w_ih, (void*)&w_hh,
                  (void*)&b_ih, (void*)&b_hh, (void*)&w_out, (void*)&b_out,
                  (void*)&out, (void*)&cnt, (void*)&hbuf};
  hipLaunchCooperativeKernel((void*)kuai_lstm, dim3(256), dim3(512), args,
                             SMEM_BYTES, stream);
}

// Round 2
// 2743.050 us; speedup vs baseline: 1.8581x; 1.8581x over previous
//
#include <hip/hip_runtime.h>
#include <hip/hip_bf16.h>
#include <stdint.h>

#define NTT   365
#define NGRID 2048
#define NXX   32

typedef __attribute__((ext_vector_type(8))) short bf16x8;
typedef __attribute__((ext_vector_type(4))) float f32x4;

// ---- LDS layout (byte offsets) ----
// x0 / h tiles are stored as 32 fragments of 1024 B: frag (rh, c) holds
// act[rows 16rh..16rh+16) x [cols 32c..32c+32), lane slot l = 16 B at
// (row&15) + 16*((col>>3)&3), i.e. exactly one ds_read_b128 per MFMA B-frag.
#define X0A_OFF   0          // x0 double buffer A: 32 frags x 1024 B
#define X0B_OFF   32768      // x0 double buffer B
#define HF_OFF    65536      // h fragment area: 32 frags x 1024 B
#define STG_OFF   98304      // h stage: 64 rows x 72 B (pad: conflict-free)
#define WOUT_OFF  102912     // w_out: 256 f32
#define BIN_OFF   103936     // b_in: 256 f32
#define SMEM_BYTES 104960

__device__ __forceinline__ int frag_off(int rh, int c) { return ((rh << 3) + c) << 10; }
__device__ __forceinline__ int el_off(int row, int col) {
  return (((row >> 4) * 8 + (col >> 5)) << 10) +
         (((((col >> 3) & 3) << 4) + (row & 15)) << 4) + ((col & 7) << 1);
}
__device__ __forceinline__ unsigned short f2bf(float f) {
  unsigned u = __builtin_bit_cast(unsigned, f);
  return (unsigned short)((u + 0x7FFFu + ((u >> 16) & 1u)) >> 16);  // RNE
}
__device__ __forceinline__ float bf2f(unsigned short s) {
  unsigned u = ((unsigned)s) << 16;
  return __builtin_bit_cast(float, u);
}
__device__ __forceinline__ float sigm(float x) {
  return 1.0f / (1.0f + exp2f(-1.4426950408889634f * x));
}
__device__ __forceinline__ float tanh_f(float x) {
  return 2.0f / (1.0f + exp2f(-2.8853900817779268f * x)) - 1.0f;
}
__device__ __forceinline__ bf16x8 pack8(float4 a, float4 b) {
  bf16x8 r;
  r[0] = (short)f2bf(a.x); r[1] = (short)f2bf(a.y);
  r[2] = (short)f2bf(a.z); r[3] = (short)f2bf(a.w);
  r[4] = (short)f2bf(b.x); r[5] = (short)f2bf(b.y);
  r[6] = (short)f2bf(b.z); r[7] = (short)f2bf(b.w);
  return r;
}

// Persistent fused LSTM.
// Grid: 256 blocks = 32 row-groups x 8 members, 512 thr = 8 waves.
// Member m owns h-cols [32m,32m+32) -> 128 gate rows, weights in VGPRs.
// Gates computed TRANSPOSED: mfma(W, act) so C-frag reg index == gate id.
// Exchange: relaxed sc1 stores to ping-pong hbuf + per-member flag words;
// consumers poll relaxed + load fragments with explicit sc0/sc1 b128 loads.
extern "C" __global__ void __launch_bounds__(512, 1)
kuai_lstm(const float* __restrict__ x, const float* __restrict__ w_in,
          const float* __restrict__ b_in, const float* __restrict__ w_ih,
          const float* __restrict__ w_hh, const float* __restrict__ b_ih,
          const float* __restrict__ b_hh, const float* __restrict__ w_out,
          const float* __restrict__ b_out, float* __restrict__ out,
          unsigned* __restrict__ flags, char* __restrict__ hbuf) {
  extern __shared__ char smem[];
  const int tid = threadIdx.x;
  const int l   = tid & 63;
  const int l15 = l & 15;
  const int l4  = l >> 4;
  const int w   = tid >> 6;   // wave 0..7
  const int wq  = w & 3;      // gate-col quarter
  const int wr  = w >> 2;     // row half

  const int bid = blockIdx.x;
  const int xcd = bid & 7;
  const int t2  = bid >> 3;
  const int q   = t2 >> 3;
  const int m   = t2 & 7;     // member 0..7
  const int grp = xcd * 4 + q;
  const int r0  = grp * 64;

  // ---------------- prologue ----------------
  if (tid < 64) {
    float4 v = *(const float4*)(w_out + tid * 4);
    *(float4*)(smem + WOUT_OFF + tid * 16) = v;
    float4 bv = *(const float4*)(b_in + tid * 4);
    *(float4*)(smem + BIN_OFF + tid * 16) = bv;
  }
  const float b_out_v = b_out[0];

  // Gate-weight fragments in VGPRs (identical math to verified round 1).
  bf16x8 Wf[2][16];
#pragma unroll
  for (int i = 0; i < 2; ++i) {
    int n  = 32 * wq + 16 * i + l15;
    int gc = (n & 3) * 256 + 32 * m + (n >> 2);
    const float* bh = w_hh + (size_t)gc * 256;
    const float* bi = w_ih + (size_t)gc * 256;
#pragma unroll
    for (int kc = 0; kc < 16; ++kc) {
      int k = kc * 32 + l4 * 8;
      const float* p = (kc < 8) ? (bh + k) : (bi + (k - 256));
      Wf[i][kc] = pack8(*(const float4*)p, *(const float4*)(p + 4));
    }
  }
  bf16x8 WinF[4];
#pragma unroll
  for (int ii = 0; ii < 4; ++ii) {
    int xct = 4 * wq + ii;
    const float* p = w_in + (size_t)(16 * xct + l15) * 32 + l4 * 8;
    WinF[ii] = pack8(*(const float4*)p, *(const float4*)(p + 4));
  }
  float bsv[2][4];
#pragma unroll
  for (int i = 0; i < 2; ++i)
#pragma unroll
    for (int r = 0; r < 4; ++r) {
      int gc = r * 256 + 32 * m + (8 * wq + 4 * i + l4);
      bsv[i][r] = b_ih[gc] + b_hh[gc];
    }

  float creg[2][2] = {{0.f, 0.f}, {0.f, 0.f}};
  const int srow = tid >> 3;
  const int sseg = tid & 7;
  __syncthreads();  // BIN/WOUT visible

  // x-phase: x0(tt) = relu(x_tt @ w_in^T + b_in) into frag-layout buffer xb
  auto xphase = [&](int tt, char* xb) {
    bf16x8 xf[2];
#pragma unroll
    for (int j = 0; j < 2; ++j) {
      const float* xp = x + ((size_t)tt * NGRID + (r0 + 32 * wr + 16 * j + l15)) * NXX + l4 * 8;
      xf[j] = pack8(*(const float4*)xp, *(const float4*)(xp + 4));
    }
#pragma unroll
    for (int ii = 0; ii < 4; ++ii) {
      f32x4 bi = *(const f32x4*)(smem + BIN_OFF + (16 * (4 * wq + ii) + 4 * l4) * 4);
#pragma unroll
      for (int j = 0; j < 2; ++j) {
        f32x4 xa = __builtin_amdgcn_mfma_f32_16x16x32_bf16(WinF[ii], xf[j], bi, 0, 0, 0);
        int row = 32 * wr + 16 * j + l15;
        int c0  = 16 * (4 * wq + ii) + 4 * l4;
        unsigned short h0 = f2bf(fmaxf(xa[0], 0.f));
        unsigned short h1 = f2bf(fmaxf(xa[1], 0.f));
        unsigned short h2 = f2bf(fmaxf(xa[2], 0.f));
        unsigned short h3 = f2bf(fmaxf(xa[3], 0.f));
        uint64_t pk = (uint64_t)h0 | ((uint64_t)h1 << 16) | ((uint64_t)h2 << 32) |
                      ((uint64_t)h3 << 48);
        *(uint64_t*)(xb + el_off(row, c0)) = pk;
      }
    }
  };

  xphase(0, smem + X0A_OFF);
  __syncthreads();

  // ---------------- time loop ----------------
  for (int t = 0; t < NTT; ++t) {
    const int p = t & 1;
    char* xb_cur = smem + (p ? X0B_OFF : X0A_OFF);
    char* xb_nxt = smem + (p ? X0A_OFF : X0B_OFF);

    // gate accumulators (reg r == gate r)
    f32x4 acc[2][2];
#pragma unroll
    for (int i = 0; i < 2; ++i)
#pragma unroll
      for (int j = 0; j < 2; ++j) {
        acc[i][j][0] = bsv[i][0]; acc[i][j][1] = bsv[i][1];
        acc[i][j][2] = bsv[i][2]; acc[i][j][3] = bsv[i][3];
      }

    // ---- x0 half of K (no peer dependence) ----
#pragma unroll
    for (int c = 0; c < 8; ++c)
#pragma unroll
      for (int j = 0; j < 2; ++j) {
        bf16x8 bfrag = *(const bf16x8*)(xb_cur + frag_off(2 * wr + j, c) + l * 16);
        acc[0][j] = __builtin_amdgcn_mfma_f32_16x16x32_bf16(Wf[0][c + 8], bfrag, acc[0][j], 0, 0, 0);
        acc[1][j] = __builtin_amdgcn_mfma_f32_16x16x32_bf16(Wf[1][c + 8], bfrag, acc[1][j], 0, 0, 0);
      }

    // ---- x-phase for t+1 (overlaps the wait for h_t peers) ----
    if (t + 1 < NTT) xphase(t + 1, xb_nxt);

    if (t > 0) {
      const int pprev = (t - 1) & 1;
      // poll only the 4 members whose chunks this wave stages
      unsigned* fl = flags + grp * 16 + pprev * 8;
      const int f0 = 4 * w;
      const int pc = (f0 + (l & 3)) & 7;
      for (;;) {
        unsigned v = __hip_atomic_load(fl + pc, __ATOMIC_RELAXED, __HIP_MEMORY_SCOPE_AGENT);
        if (__all((int)(v >= (unsigned)t))) break;
        __builtin_amdgcn_s_sleep(1);
      }
      // dedup fragment load: wave w stages frags 4w..4w+3 (one sc1 b128/lane)
      const char* hb = hbuf + (size_t)pprev * (NGRID * 512);
      const char* p0 = hb + (size_t)(r0 + ((f0 + 0) >> 3) * 16 + l15) * 512 + ((f0 + 0) & 7) * 64 + l4 * 16;
      const char* p1 = hb + (size_t)(r0 + ((f0 + 1) >> 3) * 16 + l15) * 512 + ((f0 + 1) & 7) * 64 + l4 * 16;
      const char* p2 = hb + (size_t)(r0 + ((f0 + 2) >> 3) * 16 + l15) * 512 + ((f0 + 2) & 7) * 64 + l4 * 16;
      const char* p3 = hb + (size_t)(r0 + ((f0 + 3) >> 3) * 16 + l15) * 512 + ((f0 + 3) & 7) * 64 + l4 * 16;
      f32x4 d0, d1, d2, d3;
      asm volatile(
          "global_load_dwordx4 %0, %4, off sc0 sc1\n\t"
          "global_load_dwordx4 %1, %5, off sc0 sc1\n\t"
          "global_load_dwordx4 %2, %6, off sc0 sc1\n\t"
          "global_load_dwordx4 %3, %7, off sc0 sc1\n\t"
          "s_waitcnt vmcnt(0)"
          : "=&v"(d0), "=&v"(d1), "=&v"(d2), "=&v"(d3)
          : "v"(p0), "v"(p1), "v"(p2), "v"(p3)
          : "memory");
      *(f32x4*)(smem + HF_OFF + (f0 + 0) * 1024 + l * 16) = d0;
      *(f32x4*)(smem + HF_OFF + (f0 + 1) * 1024 + l * 16) = d1;
      *(f32x4*)(smem + HF_OFF + (f0 + 2) * 1024 + l * 16) = d2;
      *(f32x4*)(smem + HF_OFF + (f0 + 3) * 1024 + l * 16) = d3;
      __syncthreads();  // barrier C: all h frags staged

      // ---- h half of K; wq==0 waves also fold out[t-1] from same frags ----
      float os0 = 0.f, os1 = 0.f;
#pragma unroll
      for (int c = 0; c < 8; ++c)
#pragma unroll
        for (int j = 0; j < 2; ++j) {
          bf16x8 hf = *(const bf16x8*)(smem + HF_OFF + frag_off(2 * wr + j, c) + l * 16);
          acc[0][j] = __builtin_amdgcn_mfma_f32_16x16x32_bf16(Wf[0][c], hf, acc[0][j], 0, 0, 0);
          acc[1][j] = __builtin_amdgcn_mfma_f32_16x16x32_bf16(Wf[1][c], hf, acc[1][j], 0, 0, 0);
          if (wq == 0) {
            const float* wv = (const float*)(smem + WOUT_OFF) + c * 32 + l4 * 8;
            float dsum = 0.f;
#pragma unroll
            for (int e = 0; e < 8; ++e) dsum += bf2f((unsigned short)hf[e]) * wv[e];
            if (j == 0) os0 += dsum; else os1 += dsum;
          }
        }
      if (wq == 0) {
        os0 += __shfl_xor(os0, 16); os0 += __shfl_xor(os0, 32);
        os1 += __shfl_xor(os1, 16); os1 += __shfl_xor(os1, 32);
        if (l4 == 0) {
          out[(size_t)(t - 1) * NGRID + (r0 + 32 * wr + l15)]      = os0 + b_out_v;
          out[(size_t)(t - 1) * NGRID + (r0 + 32 * wr + 16 + l15)] = os1 + b_out_v;
        }
      }
    }

    // ---- nonlinearities (regs 0..3 = i,f,g,o) ----
#pragma unroll
    for (int i = 0; i < 2; ++i)
#pragma unroll
      for (int j = 0; j < 2; ++j) {
        float gi = acc[i][j][0], gf = acc[i][j][1], gg = acc[i][j][2], go = acc[i][j][3];
        float cn = sigm(gf) * creg[i][j] + sigm(gi) * tanh_f(gg);
        float hn = sigm(go) * tanh_f(cn);
        creg[i][j] = cn;
        int row = 32 * wr + 16 * j + l15;
        int jjl = 8 * wq + 4 * i + l4;
        *(unsigned short*)(smem + STG_OFF + row * 72 + jjl * 2) = f2bf(hn);
      }
    __syncthreads();  // barrier A: stage complete

    // ---- publish own 32-col chunk (relaxed sc1), drain, flag ----
    {
      uint64_t pv = *(const uint64_t*)(smem + STG_OFF + srow * 72 + sseg * 8);
      char* dst = hbuf + (size_t)p * (NGRID * 512) + (size_t)(r0 + srow) * 512 + m * 64 + sseg * 8;
      __hip_atomic_store((unsigned long long*)dst, (unsigned long long)pv,
                         __ATOMIC_RELAXED, __HIP_MEMORY_SCOPE_AGENT);
    }
    asm volatile("s_waitcnt vmcnt(0)" ::: "memory");
    __syncthreads();  // barrier B: all waves drained
    if (tid == 0)
      __hip_atomic_store(flags + grp * 16 + p * 8 + m, (unsigned)(t + 1),
                         __ATOMIC_RELAXED, __HIP_MEMORY_SCOPE_AGENT);
  }

  // ---------------- epilogue: out[NT-1] ----------------
  {
    const int pprev = (NTT - 1) & 1;
    unsigned* fl = flags + grp * 16 + pprev * 8;
    const int f0 = 4 * w;
    const int pc = (f0 + (l & 3)) & 7;
    for (;;) {
      unsigned v = __hip_atomic_load(fl + pc, __ATOMIC_RELAXED, __HIP_MEMORY_SCOPE_AGENT);
      if (__all((int)(v >= (unsigned)NTT))) break;
      __builtin_amdgcn_s_sleep(1);
    }
    const char* hb = hbuf + (size_t)pprev * (NGRID * 512);
    const char* p0 = hb + (size_t)(r0 + ((f0 + 0) >> 3) * 16 + l15) * 512 + ((f0 + 0) & 7) * 64 + l4 * 16;
    const char* p1 = hb + (size_t)(r0 + ((f0 + 1) >> 3) * 16 + l15) * 512 + ((f0 + 1) & 7) * 64 + l4 * 16;
    const char* p2 = hb + (size_t)(r0 + ((f0 + 2) >> 3) * 16 + l15) * 512 + ((f0 + 2) & 7) * 64 + l4 * 16;
    const char* p3 = hb + (size_t)(r0 + ((f0 + 3) >> 3) * 16 + l15) * 512 + ((f0 + 3) & 7) * 64 + l4 * 16;
    f32x4 d0, d1, d2, d3;
    asm volatile(
        "global_load_dwordx4 %0, %4, off sc0 sc1\n\t"
        "global_load_dwordx4 %1, %5, off sc0 sc1\n\t"
        "global_load_dwordx4 %2, %6, off sc0 sc1\n\t"
        "global_load_dwordx4 %3, %7, off sc0 sc1\n\t"
        "s_waitcnt vmcnt(0)"
        : "=&v"(d0), "=&v"(d1), "=&v"(d2), "=&v"(d3)
        : "v"(p0), "v"(p1), "v"(p2), "v"(p3)
        : "memory");
    *(f32x4*)(smem + HF_OFF + (f0 + 0) * 1024 + l * 16) = d0;
    *(f32x4*)(smem + HF_OFF + (f0 + 1) * 1024 + l * 16) = d1;
    *(f32x4*)(smem + HF_OFF + (f0 + 2) * 1024 + l * 16) = d2;
    *(f32x4*)(smem + HF_OFF + (f0 + 3) * 1024 + l * 16) = d3;
    __syncthreads();
    if (wq == 0) {
      float os0 = 0.f, os1 = 0.f;
#pragma unroll
      for (int c = 0; c < 8; ++c)
#pragma unroll
        for (int j = 0; j < 2; ++j) {
          bf16x8 hf = *(const bf16x8*)(smem + HF_OFF + frag_off(2 * wr + j, c) + l * 16);
          const float* wv = (const float*)(smem + WOUT_OFF) + c * 32 + l4 * 8;
          float dsum = 0.f;
#pragma unroll
          for (int e = 0; e < 8; ++e) dsum += bf2f((unsigned short)hf[e]) * wv[e];
          if (j == 0) os0 += dsum; else os1 += dsum;
        }
      os0 += __shfl_xor(os0, 16); os0 += __shfl_xor(os0, 32);
      os1 += __shfl_xor(os1, 16); os1 += __shfl_xor(os1, 32);
      if (l4 == 0) {
        out[(size_t)(NTT - 1) * NGRID + (r0 + 32 * wr + l15)]      = os0 + b_out_v;
        out[(size_t)(NTT - 1) * NGRID + (r0 + 32 * wr + 16 + l15)] = os1 + b_out_v;
      }
    }
  }
}

extern "C" void kernel_launch(void* const* d_in, const int* in_sizes, int n_in,
                              void* d_out, int out_size, void* d_ws, size_t ws_size,
                              hipStream_t stream) {
  (void)in_sizes; (void)n_in; (void)out_size; (void)ws_size;
  const float* x     = (const float*)d_in[0];
  const float* w_in  = (const float*)d_in[1];
  const float* b_in  = (const float*)d_in[2];
  const float* w_ih  = (const float*)d_in[3];
  const float* w_hh  = (const float*)d_in[4];
  const float* b_ih  = (const float*)d_in[5];
  const float* b_hh  = (const float*)d_in[6];
  const float* w_out = (const float*)d_in[7];
  const float* b_out = (const float*)d_in[8];
  float* out = (float*)d_out;

  // ws: [0,4096) flags (zeroed per launch); [4096, +2MB) h ping-pong (bf16)
  unsigned* flags = (unsigned*)d_ws;
  char* hbuf = (char*)d_ws + 4096;

  hipMemsetAsync(d_ws, 0, 4096, stream);
  hipFuncSetAttribute((const void*)kuai_lstm,
                      hipFuncAttributeMaxDynamicSharedMemorySize, SMEM_BYTES);

  void* args[] = {(void*)&x, (void*)&w_in, (void*)&b_in, (void*)&w_ih, (void*)&w_hh,
                  (void*)&b_ih, (void*)&b_hh, (void*)&w_out, (void*)&b_out,
                  (void*)&out, (void*)&flags, (void*)&hbuf};
  hipLaunchCooperativeKernel((void*)kuai_lstm, dim3(256), dim3(512), args,
                             SMEM_BYTES, stream);
}